// Round 13
// baseline (200.367 us; speedup 1.0000x reference)
//
#include <hip/hip_runtime.h>
#include <stdint.h>

#define NROWS 16384   // 16*32*32 spatial positions
#define NCODES 8192
#define DIM 256
// score = 1024 + dot - ||e||^2/2  (higher = closer). bf16 dist-error sigma
// ~0.05 in score units. EPS_S = 0.4 (8 sigma one-sided, validated absmax=0
// across both sessions). SM = 0.5 (7.1 sigma on the gap diff; validated R9).
// R8 f16 lesson: margins are validated AGAINST the bf16 error model; dtype
// swaps change the model and void the validation. bf16 is frozen.
#define EPS_S 0.4f
#define SM 0.5f

typedef __attribute__((ext_vector_type(8))) short bf16x8;    // 8 bf16 = 4 VGPRs
typedef __attribute__((ext_vector_type(16))) float f32x16;   // 32x32 C/D frag
typedef unsigned int uint32;

__device__ __forceinline__ unsigned short f2bf(float f) {
  union { float f; unsigned int u; } v; v.f = f;
  unsigned int u = v.u;
  return (unsigned short)((u + 0x7FFFu + ((u >> 16) & 1u)) >> 16);  // RNE
}

// exact-path u64 key = order-preserving dist bits << 32 | idx (min = best+lowest idx)
__device__ __forceinline__ unsigned long long packdi(float d, int idx) {
  unsigned int u = __float_as_uint(d);
  u = (u & 0x80000000u) ? ~u : (u | 0x80000000u);
  return ((unsigned long long)u << 32) | (unsigned int)idx;
}
__device__ __forceinline__ unsigned long long u64min(unsigned long long a,
                                                     unsigned long long b) {
  return a < b ? a : b;
}
__device__ __forceinline__ unsigned long long shflx64(unsigned long long v, int m) {
  int lo = __shfl_xor((int)(unsigned int)v, m);
  int hi = __shfl_xor((int)(v >> 32), m);
  return ((unsigned long long)(unsigned int)hi << 32) | (unsigned int)lo;
}
__device__ __forceinline__ uint32 umax(uint32 a, uint32 b) { return a > b ? a : b; }
__device__ __forceinline__ uint32 umin(uint32 a, uint32 b) { return a < b ? a : b; }

// async global->LDS, 16B per lane; LDS dest is wave-uniform base + lane*16
__device__ __forceinline__ void glds16(const ushort* g, ushort* l) {
  __builtin_amdgcn_global_load_lds(
      (const __attribute__((address_space(1))) unsigned int*)g,
      (__attribute__((address_space(3))) unsigned int*)l, 16, 0, 0);
}

// ---- Phase 0 (fused): z transpose+bf16, codebook bf16+norms ----------------
// R10's vectorized post-transpose stores (float4 + ushort4), validated.
__global__ __launch_bounds__(256) void prep(const float* __restrict__ z,
                                            const float* __restrict__ cb,
                                            float* __restrict__ flatz,
                                            ushort* __restrict__ zb,
                                            ushort* __restrict__ eb,
                                            float* __restrict__ enorm) {
  __shared__ float t[32][33];
  const int blk = blockIdx.x;
  if (blk < 4096) {  // prep_z part: NCHW -> (row, d), fp32 copy into zq
    const int tx = threadIdx.x & 31, ty = threadIdx.x >> 5;  // 32 x 8 loads
    const int ht = blk & 31, ct = (blk >> 5) & 7, b = blk >> 8;
    const float* src = z + (size_t)b * 262144 + (size_t)(ct * 32) * 1024 + ht * 32;
#pragma unroll
    for (int i = 0; i < 4; ++i) {
      int c = ty + i * 8;
      t[c][tx] = src[c * 1024 + tx];
    }
    __syncthreads();
    const int r = threadIdx.x >> 3, q = threadIdx.x & 7;  // row r, chan quad q
    float4 vv;
    vv.x = t[q * 4 + 0][r];
    vv.y = t[q * 4 + 1][r];
    vv.z = t[q * 4 + 2][r];
    vv.w = t[q * 4 + 3][r];
    const int row = b * 1024 + ht * 32 + r;
    *(float4*)(flatz + (size_t)row * 256 + ct * 32 + q * 4) = vv;
    ushort4 o;
    o.x = f2bf(vv.x); o.y = f2bf(vv.y); o.z = f2bf(vv.z); o.w = f2bf(vv.w);
    *(ushort4*)(zb + (size_t)row * 256 + ct * 32 + q * 4) = o;
  } else {  // prep_cb part
    const int lane = threadIdx.x & 63, wave = threadIdx.x >> 6;
    const int code = (blk - 4096) * 4 + wave;
    float4 v = *(const float4*)(cb + (size_t)code * 256 + lane * 4);
    ushort4 o;
    o.x = f2bf(v.x); o.y = f2bf(v.y); o.z = f2bf(v.z); o.w = f2bf(v.w);
    *(ushort4*)(eb + (size_t)code * 256 + lane * 4) = o;
    float ss = v.x * v.x + v.y * v.y + v.z * v.z + v.w * v.w;
#pragma unroll
    for (int s = 1; s < 64; s <<= 1) ss += __shfl_xor(ss, s);
    if (lane == 0) enorm[code] = ss;
  }
}

// acc init (256-code wave tile, acc[8]): 1024 - 0.5*||e||^2 through the
// 32x32 C/D layout (reg p covers code row (p&3)+8*(p>>2)+4*lg of frag m
// [m74/m101]). epb = enorm + code0 (GLOBAL, L2-hot; VMEM loads only
// OVER-count later vmcnt(0) waits -- safe).
__device__ __forceinline__ void init_acc(f32x16 acc[8],
                                         const float* __restrict__ epb,
                                         int lg) {
#pragma unroll
  for (int m = 0; m < 8; ++m) {
    const float* ep = epb + m * 32 + 4 * lg;
    float4 e0 = *(const float4*)(ep);
    float4 e1 = *(const float4*)(ep + 8);
    float4 e2 = *(const float4*)(ep + 16);
    float4 e3 = *(const float4*)(ep + 24);
    f32x16 c0;
    c0[0]  = 1024.f - 0.5f * e0.x; c0[1]  = 1024.f - 0.5f * e0.y;
    c0[2]  = 1024.f - 0.5f * e0.z; c0[3]  = 1024.f - 0.5f * e0.w;
    c0[4]  = 1024.f - 0.5f * e1.x; c0[5]  = 1024.f - 0.5f * e1.y;
    c0[6]  = 1024.f - 0.5f * e1.z; c0[7]  = 1024.f - 0.5f * e1.w;
    c0[8]  = 1024.f - 0.5f * e2.x; c0[9]  = 1024.f - 0.5f * e2.y;
    c0[10] = 1024.f - 0.5f * e2.z; c0[11] = 1024.f - 0.5f * e2.w;
    c0[12] = 1024.f - 0.5f * e3.x; c0[13] = 1024.f - 0.5f * e3.y;
    c0[14] = 1024.f - 0.5f * e3.z; c0[15] = 1024.f - 0.5f * e3.w;
    acc[m] = c0;
  }
}

// epilogue (256-code x 32-row wave tile): per (m,hc) frag-chunk of 16 codes
// the VALIDATED top-2 chain verbatim (lane holds 8 regs hc*8+p, id =
// (p&3) | lg<<2 | (p>>2)<<3; u32 chains + one shfl(32) merge; flag bit 4 =
// gap > SM). Wave covers chunk16s cid0b+0..15 of rows zrowb+wave*32+l31;
// post-merge res[] is lg-uniform -> lg=0 stores chunks 0..7, lg=1 8..15.
__device__ __forceinline__ void epilogue(const f32x16 acc[8],
                                         uint32* __restrict__ bm, int cid0b,
                                         int zrowb, int wave, int l31, int lg) {
  uint32 res[16];
#pragma unroll
  for (int m = 0; m < 8; ++m)
#pragma unroll
    for (int hc = 0; hc < 2; ++hc) {
      uint32 m1 = 0, m2 = 0;
#pragma unroll
      for (int p = 0; p < 8; ++p) {
        uint32 id = (uint32)((p & 3) | (lg << 2) | ((p >> 2) << 3));
        uint32 pv = (__float_as_uint(acc[m][hc * 8 + p]) & ~31u) | id;
        m2 = umax(m2, umin(m1, pv));
        m1 = umax(m1, pv);
      }
      uint32 o1 = (uint32)__shfl_xor((int)m1, 32);
      uint32 o2 = (uint32)__shfl_xor((int)m2, 32);
      m2 = umax(umax(m2, o2), umin(m1, o1));
      m1 = umax(m1, o1);
      float s1 = __uint_as_float(m1 & ~31u);
      float s2 = __uint_as_float(m2 & ~31u);
      res[m * 2 + hc] = (s1 - s2 > SM) ? (m1 | 16u) : m1;
    }
  const int zr = zrowb + wave * 32 + l31;
  uint32* dst = bm + (size_t)zr * 512 + cid0b + lg * 8;
  uint4 oA, oB;  // static res indices (rule #20); values lg-uniform
  oA.x = lg ? res[8]  : res[0];
  oA.y = lg ? res[9]  : res[1];
  oA.z = lg ? res[10] : res[2];
  oA.w = lg ? res[11] : res[3];
  oB.x = lg ? res[12] : res[4];
  oB.y = lg ? res[13] : res[5];
  oB.z = lg ? res[14] : res[6];
  oB.w = lg ? res[15] : res[7];
  *(uint4*)(dst) = oA;
  *(uint4*)(dst + 4) = oB;
}

// ---- Phase 1: bf16 MFMA score GEMM — BARRIER-FREE per-wave-private B ring --
// R12 thesis (from the R11 accounting): staging is no longer the binder
// (288 MB -> predicted 47 us, measured 88.7); the ~1300 cyc/phase residual
// is the block-wide barrier convoy. Remove it: A stays LDS-resident
// (128 KiB, read-only after one syncthreads); B becomes PER-WAVE PRIVATE --
// wave tile 256 codes x 32 rows (acc[8] = 128 VGPR), each wave streams its
// own 2 KB B chunks through a private 2-slot ring (8 x 4 KB = 32 KB; total
// LDS = 160 KB exactly). Sealing = the wave's own vmcnt(0); NO s_barrier in
// the main loop -- waves free-run.
// Hazard audit: phase c's glds writes slot s^1; the last reads of s^1 were
// phase c-1's, drained by compiler lgkm waits before phase c-1's MFMA which
// precedes the glds in program order. Next-phase reads of s^1 follow the
// vmcnt(0) seal (asm "memory" clobber stops compiler hoisting).
// A layout/swizzle/read = R11-verbatim; B unit scheme = R3-verbatim at
// 32-row scale (g = slot ^ ((row>>1)&3), both-sides; uniform bank quads).
// Grid 256 = 32 cg x 8 yg; 1 block/CU; 64 phases (8 panels x 8 k-chunks).
__global__ __launch_bounds__(512, 2) void vq_gemm(const ushort* __restrict__ eb,
                                                  const ushort* __restrict__ zb,
                                                  const float* __restrict__ enorm,
                                                  uint32* __restrict__ bm) {
  __shared__ __align__(16) ushort Am[65536];   // 256 codes x 256 k = 128 KiB
  __shared__ __align__(16) ushort Bp[16384];   // 8 waves x 2 slots x 2 KB
  const int tid = threadIdx.x;
  const int wave = tid >> 6, lane = tid & 63;
  const int l31 = lane & 31, lg = lane >> 5;
  const int cg = blockIdx.x & 31, yg = blockIdx.x >> 5;
  const int code0 = cg * 256;
  const int zrow00 = yg * 2048;   // block's rows: 8 panels of 256
  const int cid0b = cg * 16;      // 16 chunk16s per block

  // ---- A staging (once, R11-verbatim): 8192 units; unit u: row = u>>5,
  // slot = u&31, global k-group g = (u&31) ^ (row&7). 16 glds16/thread.
#pragma unroll
  for (int j = 0; j < 16; ++j) {
    const int u = tid + j * 512;
    const int row = u >> 5;
    const int g = (u & 31) ^ (row & 7);
    glds16(eb + (size_t)(code0 + row) * 256 + g * 8,
           Am + (wave * 64 + j * 512) * 8);
  }

  // ---- B per-wave staging: wave owns rows wave*32..+32 of each panel.
  // Chunk = 128 units (2 KB): unit u: row = u>>2 (0..31), slot = u&3,
  // g = (u&3) ^ ((u>>3)&3). Instr0 covers units 0..63 (rows 0..15),
  // instr1 units 64..127 (rows 16..31, same g formula).
  const ushort* bS0 = zb + (size_t)(zrow00 + wave * 32 + (lane >> 2)) * 256 +
                      (((lane & 3) ^ ((lane >> 3) & 3))) * 8;
  const ushort* bS1 = bS0 + 16 * 256;  // rows +16
  ushort* Bw = Bp + wave * 2048;       // [slot*1024 + row*32 + slot16*8]

  // prologue: B chunk 0 -> slot 0
  glds16(bS0, Bw);
  glds16(bS1, Bw + 512);

  asm volatile("s_waitcnt vmcnt(0)" ::: "memory");  // A + B0 resident
  __syncthreads();  // the ONLY block-wide barrier

  f32x16 acc[8];
  init_acc(acc, enorm + code0, lg);

  // read addressing. A: row = m*32 + l31 (row&7 == l31&7), frag (kc,ks)
  // k-group kc*4 + ks*2 + lg at slot g ^ (l31&7). B: row = l31 (64-B rows,
  // 4 slots), k-group 2ks+lg at slot g ^ ((l31>>1)&3).
  const int swzA = l31 & 7;
  const int swzB = (l31 >> 1) & 3;
  const int colu0 = ((0 | lg) ^ swzB) * 8;   // B ks=0
  const int colu1 = ((2 | lg) ^ swzB) * 8;   // B ks=1
  const int browp = l31 * 32;

#pragma unroll 1
  for (int yp = 0; yp < 8; ++yp) {
    if (yp > 0) {  // finish previous panel (stores join the vmcnt stream)
      epilogue(acc, bm, cid0b, zrow00 + (yp - 1) * 256, wave, l31, lg);
      init_acc(acc, enorm + code0, lg);
    }
#pragma unroll
    for (int kc = 0; kc < 8; ++kc) {
      const int c = yp * 8 + kc;
      const int s = c & 1;
      // 1) issue own B chunk c+1 into private slot s^1 (hazard-free; max
      // slack: sealed at phase end after reads + MFMA)
      if (c < 63) {
        const size_t off = (size_t)((c + 1) >> 3) * 65536 +
                           (size_t)((c + 1) & 7) * 32;
        glds16(bS0 + off, Bw + (s ^ 1) * 1024);
        glds16(bS1 + off, Bw + (s ^ 1) * 1024 + 512);
      }
      // 2) reads: 16 A frags (resident) + 2 B frags (own, sealed last phase)
      bf16x8 a0[8], a1[8], b0, b1;
#pragma unroll
      for (int m = 0; m < 8; ++m) {
        a0[m] = *(const bf16x8*)&Am[(m * 32 + l31) * 256 +
                                    (((kc * 4 + 0) | lg) ^ swzA) * 8];
        a1[m] = *(const bf16x8*)&Am[(m * 32 + l31) * 256 +
                                    (((kc * 4 + 2) | lg) ^ swzA) * 8];
      }
      b0 = *(const bf16x8*)&Bp[wave * 2048 + s * 1024 + browp + colu0];
      b1 = *(const bf16x8*)&Bp[wave * 2048 + s * 1024 + browp + colu1];
      // 3) 16 MFMA (8 independent acc chains; compiler inserts lgkm waits)
      __builtin_amdgcn_s_setprio(1);
#pragma unroll
      for (int m = 0; m < 8; ++m)
        acc[m] = __builtin_amdgcn_mfma_f32_32x32x16_bf16(a0[m], b0, acc[m],
                                                         0, 0, 0);
#pragma unroll
      for (int m = 0; m < 8; ++m)
        acc[m] = __builtin_amdgcn_mfma_f32_32x32x16_bf16(a1[m], b1, acc[m],
                                                         0, 0, 0);
      __builtin_amdgcn_s_setprio(0);
      // 4) seal own chunk c+1 -- NO barrier (private buffer)
      if (c < 63) {
        asm volatile("s_waitcnt vmcnt(0)" ::: "memory");
      }
    }
  }
  epilogue(acc, bm, cid0b, zrow00 + 7 * 256, wave, l31, lg);
}

// exact fp32 distances for one 16-code chunk; summation order / lane split /
// tie-break bit-identical to the validated slow path.
__device__ __forceinline__ unsigned long long chunk_exact(
    int chunk, const float* __restrict__ zrow, const float* __restrict__ cb,
    const float* __restrict__ enorm, int lane) {
  const int code = chunk * 16 + (lane >> 2);
  const float* zp = zrow + (lane & 3) * 64;
  const float* cp = cb + (size_t)code * 256 + (lane & 3) * 64;
  float s = 0.f;
#pragma unroll
  for (int d = 0; d < 64; d += 4) {
    float4 zv = *(const float4*)(zp + d);
    float4 cv = *(const float4*)(cp + d);
    s = fmaf(zv.x, cv.x, s); s = fmaf(zv.y, cv.y, s);
    s = fmaf(zv.z, cv.z, s); s = fmaf(zv.w, cv.w, s);
  }
  s += __shfl_xor(s, 1);
  s += __shfl_xor(s, 2);
  float dist = fmaf(-2.f, s, enorm[code]);
  unsigned long long key = ((lane & 3) == 0) ? packdi(dist, code) : ~0ull;
#pragma unroll
  for (int m = 1; m < 64; m <<= 1) key = u64min(key, shflx64(key, m));
  return key;  // wave-uniform
}

// ---- Phase 2: one wave per row over 512 chunk16 maxima (validated verbatim) -
__global__ __launch_bounds__(256) void vq_sel(const uint32* __restrict__ bm,
                                              const float* __restrict__ flatz,
                                              const float* __restrict__ cb,
                                              const float* __restrict__ enorm,
                                              float* __restrict__ zq,
                                              float* __restrict__ oidx) {
  const int lane = threadIdx.x & 63;
  const int row = blockIdx.x * 4 + (threadIdx.x >> 6);
  uint4 va = *(const uint4*)(bm + (size_t)row * 512 + lane * 8);
  uint4 vb = *(const uint4*)(bm + (size_t)row * 512 + lane * 8 + 4);
  uint32 v[8] = {va.x, va.y, va.z, va.w, vb.x, vb.y, vb.z, vb.w};
  uint32 m1 = 0, m2 = 0; int ch = 0;
#pragma unroll
  for (int s = 0; s < 8; ++s) {
    uint32 pv = v[s];
    m2 = umax(m2, umin(m1, pv));
    ch = (pv > m1) ? (lane * 8 + s) : ch;
    m1 = umax(m1, pv);
  }
#pragma unroll
  for (int m = 1; m < 64; m <<= 1) {
    uint32 o1 = (uint32)__shfl_xor((int)m1, m);
    uint32 o2 = (uint32)__shfl_xor((int)m2, m);
    int oc = __shfl_xor(ch, m);
    m2 = umax(umax(m2, o2), umin(m1, o1));
    ch = (o1 > m1) ? oc : ch;
    m1 = umax(m1, o1);
  }
  // all wave-uniform now
  float s1 = __uint_as_float(m1 & ~31u);
  float s2 = __uint_as_float(m2 & ~31u);
  int idx;
  if ((m1 & 16u) && (s1 - s2 > SM)) {
    idx = ch * 16 + (int)(m1 & 15u);  // provably the exact argmin
  } else {
    const float* zrow = flatz + (size_t)row * 256;
    unsigned long long key = chunk_exact(ch, zrow, cb, enorm, lane);
    float dbest;
    { unsigned int u = (unsigned int)(key >> 32);
      u = (u & 0x80000000u) ? (u & 0x7FFFFFFFu) : ~u;
      dbest = __uint_as_float(u); }
    float thr = (1024.f - 0.5f * dbest) - EPS_S;  // window lower bound
#pragma unroll
    for (int s = 0; s < 8; ++s) {
      bool cand = __uint_as_float(v[s] & ~31u) >= thr;
      unsigned long long mk = __ballot(cand);
      while (mk) {
        int L = __ffsll(mk) - 1;
        mk &= mk - 1;
        int c2 = L * 8 + s;
        if (c2 == ch) continue;
        key = u64min(key, chunk_exact(c2, zrow, cb, enorm, lane));
      }
    }
    idx = (int)(key & 0xFFFFFFFFull);
  }
  if (lane == 0) oidx[row] = (float)idx;
  float4 val = *(const float4*)(cb + (size_t)idx * 256 + lane * 4);
  *(float4*)(zq + (size_t)row * 256 + lane * 4) = val;  // exact fp32 gather
}

// ---- launch ----------------------------------------------------------------
extern "C" void kernel_launch(void* const* d_in, const int* in_sizes, int n_in,
                              void* d_out, int out_size, void* d_ws, size_t ws_size,
                              hipStream_t stream) {
  const float* z = (const float*)d_in[0];   // (16,256,32,32) fp32
  const float* cb = (const float*)d_in[1];  // (8192,256) fp32
  char* ws = (char*)d_ws;
  // ws: zb 8M@0 | eb 4M@8M | enorm 32K@12M | bm 32M@13M  (45 MB, proven fit)
  ushort* zb = (ushort*)(ws);
  ushort* eb = (ushort*)(ws + (8u << 20));
  float* enorm = (float*)(ws + (12u << 20));
  uint32* bm = (uint32*)(ws + (13u << 20));
  float* zq = (float*)d_out;               // (16384,256) fp32
  float* oidx = zq + (size_t)NROWS * DIM;  // (16384,) as fp32 values
  float* flatz = zq;  // NHWC fp32 z lives in zq until vq_sel overwrites per-row

  prep<<<4096 + NCODES / 4, 256, 0, stream>>>(z, cb, flatz, zb, eb, enorm);
  vq_gemm<<<256, 512, 0, stream>>>(eb, zb, enorm, bm);
  vq_sel<<<NROWS / 4, 256, 0, stream>>>(bm, flatz, cb, enorm, zq, oidx);
}